// Round 2
// baseline (2274.821 us; speedup 1.0000x reference)
//
#include <hip/hip_runtime.h>

// SARDecoder on MI355X (gfx950). Dtype-robust: a detector kernel decides at
// runtime whether float inputs are bf16 or fp32 (flag in workspace), inputs
// are canonicalized once, and the output is written in the matching dtype.
//
// Pipeline:
//  0) detect dtype; canonicalize inputs (bf16 for MFMA operands, fp32 for
//     scalar-read tensors)
//  1) transpose weights (BT layout for MFMA B-fragments)
//  2) conv3x3 fproj via 9-tap shifted MFMA GEMM (timestep invariant)
//  3) E0 = embed_W @ k0 (one-hot gather trick)
//  4) 34x lstm_stage: stage0(t) and stage1(t-1) in one launch (independent),
//     gate-fused MFMA GEMM (wave = gate) + in-block LSTM pointwise
//  5) HP = H1all @ Wh ; fused tanh-attention + softmax ; glimpse ; logits

typedef __bf16 bf16;
typedef bf16 bf16x8 __attribute__((ext_vector_type(8)));
typedef float f32x4 __attribute__((ext_vector_type(4)));

#define MFMA16(a, b, c) __builtin_amdgcn_mfma_f32_16x16x32_bf16((a), (b), (c), 0, 0, 0)

__device__ __forceinline__ float b2f(unsigned short u) {
    return __uint_as_float(((unsigned int)u) << 16);
}
__device__ __forceinline__ unsigned short f2b(float f) {
    unsigned int x = __float_as_uint(f);
    unsigned int r = (x + 0x7fffu + ((x >> 16) & 1u)) >> 16;   // RNE
    return (unsigned short)r;
}
__device__ __forceinline__ float sigf(float x) {
    return 1.0f / (1.0f + expf(-x));
}

// ------------------------------------------------------------ dtype detect
// flag = 1 if inputs are fp32, 0 if bf16. Even-index ushorts of a bf16 array
// are bf16 values (exponent ~127); of an fp32 array they are mantissa halves
// (uniform bits). Count plausible exponents among 64 even-index samples.
__global__ void detect_dtype(const void* __restrict__ feat, int* __restrict__ flag) {
    if (threadIdx.x == 0 && blockIdx.x == 0) {
        const ushort* u = (const ushort*)feat;
        int cnt = 0;
        for (int i = 0; i < 128; i += 2) {
            const int e = (u[i] >> 7) & 0xFF;
            if (e >= 96 && e <= 150) ++cnt;
        }
        *flag = (cnt >= 40) ? 0 : 1;
    }
}

// ------------------------------------------------------------ converters
__global__ __launch_bounds__(256) void cvt_bf16(
    const void* __restrict__ src, ushort* __restrict__ dst, int n,
    const int* __restrict__ flag) {
    const int i = blockIdx.x * 256 + threadIdx.x;
    if (i >= n) return;
    if (*flag) dst[i] = f2b(((const float*)src)[i]);
    else       dst[i] = ((const ushort*)src)[i];
}

__global__ __launch_bounds__(256) void cvt_f32(
    const void* __restrict__ src, float* __restrict__ dst, int n,
    const int* __restrict__ flag) {
    const int i = blockIdx.x * 256 + threadIdx.x;
    if (i >= n) return;
    if (*flag) dst[i] = ((const float*)src)[i];
    else       dst[i] = b2f(((const ushort*)src)[i]);
}

// ------------------------------------------------------------ transpose
// in: R x C (bf16 or fp32 per flag) -> out: C x R in bf16
__global__ __launch_bounds__(256) void transpose_any(
    const void* __restrict__ in, ushort* __restrict__ out, int R, int C,
    const int* __restrict__ flag) {
    __shared__ float s[32][33];
    const int f32 = *flag;
    const int nbc = C >> 5;
    const int rb = blockIdx.x / nbc, cb = blockIdx.x % nbc;
    const int tx = threadIdx.x & 31, ty = threadIdx.x >> 5;
#pragma unroll
    for (int k = 0; k < 4; ++k) {
        const size_t idx = (size_t)(rb * 32 + ty + k * 8) * C + cb * 32 + tx;
        s[ty + k * 8][tx] = f32 ? ((const float*)in)[idx] : b2f(((const ushort*)in)[idx]);
    }
    __syncthreads();
#pragma unroll
    for (int k = 0; k < 4; ++k)
        out[(size_t)(cb * 32 + ty + k * 8) * R + rb * 32 + tx] = f2b(s[tx][ty + k * 8]);
}

// ------------------------------------------------------------ conv fproj
// fproj[b,y,x,a] = bf[a] + sum_{dy,dx,c} feat[b,y+dy-1,x+dx-1,c]*Wf[dy,dx,c,a]
// GEMM: M=32768 (b*256+p), N=512, K=9*512 tap-major, WfT[a][tap*512+c].
__global__ __launch_bounds__(256) void conv_fproj(
    const ushort* __restrict__ feat, const ushort* __restrict__ WfT,
    const float* __restrict__ bff, ushort* __restrict__ fproj) {
    __shared__ __align__(16) bf16 As[128][72];
    __shared__ __align__(16) bf16 Bs[128][72];
    const int tid = threadIdx.x;
    const int rb = blockIdx.x >> 2;
    const int nb = blockIdx.x & 3;
    const int b = rb >> 1;
    const int p0 = (rb & 1) << 7;
    const int ar = tid >> 1;
    const int ah = (tid & 1) << 5;
    const int p = p0 + ar, y = p >> 5, x = p & 31;
    const int w = tid >> 6, lane = tid & 63, l15 = lane & 15, q = lane >> 4;
    const int wr = (w >> 1) << 6, wc = (w & 1) << 6;
    f32x4 acc[4][4] = {};
    for (int kb = 0; kb < 72; ++kb) {
        const int tap = kb >> 3, c0 = (kb & 7) << 6;
        const int yy = y + tap / 3 - 1, xx = x + tap % 3 - 1;
        const bool valid = (yy >= 0) && (yy < 8) && (xx >= 0) && (xx < 32);
        const int yc = valid ? yy : 0, xc = valid ? xx : 0;   // clamped, never OOB
        const uint4 z4 = {0u, 0u, 0u, 0u};
        const uint4* asrc = (const uint4*)(feat + ((size_t)((b * 8 + yc) * 32 + xc) * 512 + c0 + ah));
        uint4 a0 = asrc[0], a1 = asrc[1], a2 = asrc[2], a3 = asrc[3];
        if (!valid) { a0 = z4; a1 = z4; a2 = z4; a3 = z4; }
        const uint4* bsrc = (const uint4*)(WfT + (size_t)(nb * 128 + ar) * 4608 + kb * 64 + ah);
        uint4 b0v = bsrc[0], b1v = bsrc[1], b2v = bsrc[2], b3v = bsrc[3];
        __syncthreads();
        *(uint4*)&As[ar][ah] = a0;
        *(uint4*)&As[ar][ah + 8] = a1;
        *(uint4*)&As[ar][ah + 16] = a2;
        *(uint4*)&As[ar][ah + 24] = a3;
        *(uint4*)&Bs[ar][ah] = b0v;
        *(uint4*)&Bs[ar][ah + 8] = b1v;
        *(uint4*)&Bs[ar][ah + 16] = b2v;
        *(uint4*)&Bs[ar][ah + 24] = b3v;
        __syncthreads();
#pragma unroll
        for (int ks = 0; ks < 64; ks += 32) {
            bf16x8 af[4], bfr[4];
#pragma unroll
            for (int i = 0; i < 4; ++i) af[i] = *(const bf16x8*)&As[wr + i * 16 + l15][ks + q * 8];
#pragma unroll
            for (int j = 0; j < 4; ++j) bfr[j] = *(const bf16x8*)&Bs[wc + j * 16 + l15][ks + q * 8];
#pragma unroll
            for (int i = 0; i < 4; ++i)
#pragma unroll
                for (int j = 0; j < 4; ++j)
                    acc[i][j] = MFMA16(af[i], bfr[j], acc[i][j]);
        }
    }
    const int rowbase = rb * 128 + wr, colbase = nb * 128 + wc;
#pragma unroll
    for (int i = 0; i < 4; ++i)
#pragma unroll
        for (int j = 0; j < 4; ++j)
#pragma unroll
            for (int rr = 0; rr < 4; ++rr) {
                const int row = rowbase + i * 16 + q * 4 + rr;
                const int col = colbase + j * 16 + l15;
                fproj[(size_t)row * 512 + col] = f2b(acc[i][j][rr] + bff[col]);
            }
}

// ------------------------------------------------------------ generic GEMM
// C[M x N] (fp32) = A[M x K] (bf16) * BT[N x K]^T. M may be ragged.
__global__ __launch_bounds__(256) void gemm_bt(
    const ushort* __restrict__ A, const ushort* __restrict__ BT,
    float* __restrict__ C, int M, int N, int K) {
    __shared__ __align__(16) bf16 As[128][72];
    __shared__ __align__(16) bf16 Bs[128][72];
    const int tid = threadIdx.x;
    const int nnb = N >> 7;
    const int rb = blockIdx.x / nnb, nb = blockIdx.x % nnb;
    const int ar = tid >> 1, ah = (tid & 1) << 5;
    const int w = tid >> 6, lane = tid & 63, l15 = lane & 15, q = lane >> 4;
    const int wr = (w >> 1) << 6, wc = (w & 1) << 6;
    const int r_glob = rb * 128 + ar;
    const bool aval = (r_glob < M);
    const int r_ld = aval ? r_glob : 0;            // clamped, never OOB
    f32x4 acc[4][4] = {};
    const int nkb = K >> 6;
    for (int kb = 0; kb < nkb; ++kb) {
        const uint4 z4 = {0u, 0u, 0u, 0u};
        const uint4* asrc = (const uint4*)(A + (size_t)r_ld * K + kb * 64 + ah);
        uint4 a0 = asrc[0], a1 = asrc[1], a2 = asrc[2], a3 = asrc[3];
        if (!aval) { a0 = z4; a1 = z4; a2 = z4; a3 = z4; }
        const uint4* bsrc = (const uint4*)(BT + (size_t)(nb * 128 + ar) * K + kb * 64 + ah);
        uint4 b0v = bsrc[0], b1v = bsrc[1], b2v = bsrc[2], b3v = bsrc[3];
        __syncthreads();
        *(uint4*)&As[ar][ah] = a0;
        *(uint4*)&As[ar][ah + 8] = a1;
        *(uint4*)&As[ar][ah + 16] = a2;
        *(uint4*)&As[ar][ah + 24] = a3;
        *(uint4*)&Bs[ar][ah] = b0v;
        *(uint4*)&Bs[ar][ah + 8] = b1v;
        *(uint4*)&Bs[ar][ah + 16] = b2v;
        *(uint4*)&Bs[ar][ah + 24] = b3v;
        __syncthreads();
#pragma unroll
        for (int ks = 0; ks < 64; ks += 32) {
            bf16x8 af[4], bfr[4];
#pragma unroll
            for (int i = 0; i < 4; ++i) af[i] = *(const bf16x8*)&As[wr + i * 16 + l15][ks + q * 8];
#pragma unroll
            for (int j = 0; j < 4; ++j) bfr[j] = *(const bf16x8*)&Bs[wc + j * 16 + l15][ks + q * 8];
#pragma unroll
            for (int i = 0; i < 4; ++i)
#pragma unroll
                for (int j = 0; j < 4; ++j)
                    acc[i][j] = MFMA16(af[i], bfr[j], acc[i][j]);
        }
    }
#pragma unroll
    for (int i = 0; i < 4; ++i)
#pragma unroll
        for (int j = 0; j < 4; ++j)
#pragma unroll
            for (int rr = 0; rr < 4; ++rr) {
                const int row = rb * 128 + wr + i * 16 + q * 4 + rr;
                const int col = nb * 128 + wc + j * 16 + l15;
                if (row < M) C[(size_t)row * N + col] = acc[i][j][rr];
            }
}

// ------------------------------------------------------------ LSTM stage
// blocks 0..63: stage0 of step t; blocks 64..127: stage1 of step t-1.
// t=-2: prime LSTM0 (holistic@k0), t=-1: prime LSTM1 (h0@k1).
// Gate-fused: wave w computes gate w's 32x32 z-tile, then LSTM pointwise.
__global__ __launch_bounds__(256) void lstm_stage(
    int t,
    const ushort* __restrict__ holistic, const int* __restrict__ gt,
    const float* __restrict__ b0f, const float* __restrict__ b1f,
    const ushort* __restrict__ k0T, const ushort* __restrict__ rk0T,
    const ushort* __restrict__ k1T, const ushort* __restrict__ rk1T,
    const float* __restrict__ E0,
    ushort* h0b0, ushort* h0b1, ushort* h1b0, ushort* h1b1,
    float* c0buf, float* c1buf, ushort* H1all) {
    const int part = blockIdx.x >> 6;
    const int bi = blockIdx.x & 63;
    const ushort *A1 = nullptr, *A2 = nullptr, *B1 = nullptr, *B2 = nullptr;
    const float* bias = nullptr;
    ushort *hout = nullptr, *hout2 = nullptr;
    float* cbuf = nullptr;
    bool useC = false, useE = false;
    int nkb = 8;
    if (part == 0) {
        if (!(t == -2 || (t >= 0 && t <= 30))) return;
        bias = b0f; cbuf = c0buf;
        if (t == -2) { A1 = holistic; B1 = k0T; hout = h0b1; }
        else {
            A1 = ((t + 1) & 1) ? h0b1 : h0b0;
            B1 = rk0T;
            hout = (t & 1) ? h0b1 : h0b0;
            useC = true; useE = true;
        }
    } else {
        if (!(t == -1 || (t >= 1 && t <= 31))) return;
        bias = b1f; cbuf = c1buf;
        if (t == -1) { A1 = h0b1; B1 = k1T; hout = h1b1; }
        else {
            const int s = t - 1;
            A1 = (s & 1) ? h0b1 : h0b0;           // h0 of step s
            A2 = ((s + 1) & 1) ? h1b1 : h1b0;     // h1 of step s-1
            B1 = k1T; B2 = rk1T;
            hout = (s & 1) ? h1b1 : h1b0;
            hout2 = H1all + (size_t)s * 65536;
            useC = true; nkb = 16;
        }
    }
    const int m0 = (bi >> 4) << 5;
    const int cc0 = (bi & 15) << 5;
    const int tid = threadIdx.x;
    const int w = tid >> 6, lane = tid & 63, l15 = lane & 15, q = lane >> 4;
    __shared__ __align__(16) bf16 As[32][72];
    __shared__ __align__(16) bf16 Bs[4][32][72];
    __shared__ float zs[4][32][33];
    f32x4 acc[2][2] = {};
    const int arr = tid >> 3, aco = (tid & 7) << 3;
    const int bn = lane >> 1, bho = (lane & 1) << 5;
    for (int kb = 0; kb < nkb; ++kb) {
        const ushort* ap = (kb < 8) ? (A1 + (size_t)(m0 + arr) * 512 + kb * 64 + aco)
                                    : (A2 + (size_t)(m0 + arr) * 512 + (kb - 8) * 64 + aco);
        uint4 av = *(const uint4*)ap;
        const ushort* bp = (kb < 8) ? (B1 + (size_t)(w * 512 + cc0 + bn) * 512 + kb * 64 + bho)
                                    : (B2 + (size_t)(w * 512 + cc0 + bn) * 512 + (kb - 8) * 64 + bho);
        uint4 bv0 = ((const uint4*)bp)[0];
        uint4 bv1 = ((const uint4*)bp)[1];
        uint4 bv2 = ((const uint4*)bp)[2];
        uint4 bv3 = ((const uint4*)bp)[3];
        __syncthreads();
        *(uint4*)&As[arr][aco] = av;
        *(uint4*)&Bs[w][bn][bho] = bv0;
        *(uint4*)&Bs[w][bn][bho + 8] = bv1;
        *(uint4*)&Bs[w][bn][bho + 16] = bv2;
        *(uint4*)&Bs[w][bn][bho + 24] = bv3;
        __syncthreads();
#pragma unroll
        for (int ks = 0; ks < 64; ks += 32) {
            bf16x8 af0 = *(const bf16x8*)&As[l15][ks + q * 8];
            bf16x8 af1 = *(const bf16x8*)&As[16 + l15][ks + q * 8];
            bf16x8 bf0 = *(const bf16x8*)&Bs[w][l15][ks + q * 8];
            bf16x8 bf1 = *(const bf16x8*)&Bs[w][16 + l15][ks + q * 8];
            acc[0][0] = MFMA16(af0, bf0, acc[0][0]);
            acc[0][1] = MFMA16(af0, bf1, acc[0][1]);
            acc[1][0] = MFMA16(af1, bf0, acc[1][0]);
            acc[1][1] = MFMA16(af1, bf1, acc[1][1]);
        }
    }
    __syncthreads();
#pragma unroll
    for (int i = 0; i < 2; ++i)
#pragma unroll
        for (int j = 0; j < 2; ++j)
#pragma unroll
            for (int rr = 0; rr < 4; ++rr)
                zs[w][i * 16 + q * 4 + rr][j * 16 + l15] = acc[i][j][rr];
    __syncthreads();
    for (int e = tid; e < 1024; e += 256) {
        const int mm = e >> 5, cc = e & 31;
        const int brow = m0 + mm, col = cc0 + cc;
        float zi = zs[0][mm][cc] + bias[col];
        float zf = zs[1][mm][cc] + bias[512 + col];
        float zg = zs[2][mm][cc] + bias[1024 + col];
        float zo = zs[3][mm][cc] + bias[1536 + col];
        if (useE) {
            const int s = (t == 0) ? 111 : gt[brow * 31 + t - 1];
            if (s >= 0 && s < 111) {
                const float* er = E0 + (size_t)s * 2048;
                zi += er[col]; zf += er[512 + col]; zg += er[1024 + col]; zo += er[1536 + col];
            }
        }
        const float cp = useC ? cbuf[brow * 512 + col] : 0.0f;
        const float c2 = sigf(zf) * cp + sigf(zi) * tanhf(zg);
        const float h = sigf(zo) * tanhf(c2);
        cbuf[brow * 512 + col] = c2;
        hout[brow * 512 + col] = f2b(h);
        if (hout2) hout2[brow * 512 + col] = f2b(h);
    }
}

// ------------------------------------------------------------ attention
// attW[t,b,p] = softmax_p( sum_c tanh(fproj[b,p,c] + HP[t,b,c]) * wa[c] )
__global__ __launch_bounds__(256) void attention_kernel(
    const ushort* __restrict__ fproj, const float* __restrict__ HP,
    const float* __restrict__ waf, float* __restrict__ attW) {
    __shared__ float hps[16][512];
    __shared__ float attL[16][256];
    __shared__ float red[8];
    const int tid = threadIdx.x;
    const int b = blockIdx.x >> 1, th = blockIdx.x & 1;
    const int t0 = th << 4, tc = th ? 15 : 16;
    for (int idx = tid; idx < tc * 512; idx += 256) {
        const int tt = idx >> 9, c = idx & 511;
        hps[tt][c] = HP[((size_t)(t0 + tt) * 128 + b) * 512 + c];
    }
    __syncthreads();
    const int w = tid >> 6, lane = tid & 63;
    const int cb = lane << 3;
    float wv[8];
#pragma unroll
    for (int j = 0; j < 8; ++j) wv[j] = waf[cb + j];
    for (int p = w; p < 256; p += 4) {
        const uint4 fv = *(const uint4*)(fproj + ((size_t)(b * 256 + p) << 9) + cb);
        float f[8];
        f[0] = b2f((unsigned short)(fv.x & 0xffff)); f[1] = b2f((unsigned short)(fv.x >> 16));
        f[2] = b2f((unsigned short)(fv.y & 0xffff)); f[3] = b2f((unsigned short)(fv.y >> 16));
        f[4] = b2f((unsigned short)(fv.z & 0xffff)); f[5] = b2f((unsigned short)(fv.z >> 16));
        f[6] = b2f((unsigned short)(fv.w & 0xffff)); f[7] = b2f((unsigned short)(fv.w >> 16));
        for (int tt = 0; tt < tc; ++tt) {
            float s = 0.f;
#pragma unroll
            for (int j = 0; j < 8; ++j)
                s += tanhf(f[j] + hps[tt][cb + j]) * wv[j];
#pragma unroll
            for (int m = 1; m < 64; m <<= 1) s += __shfl_xor(s, m);
            if (lane == 0) attL[tt][p] = s;
        }
    }
    __syncthreads();
    for (int tt = 0; tt < tc; ++tt) {
        const float v = attL[tt][tid];
        float mx = v;
#pragma unroll
        for (int m = 1; m < 64; m <<= 1) mx = fmaxf(mx, __shfl_xor(mx, m));
        if (lane == 0) red[w] = mx;
        __syncthreads();
        mx = fmaxf(fmaxf(red[0], red[1]), fmaxf(red[2], red[3]));
        const float e = expf(v - mx);
        float sm = e;
#pragma unroll
        for (int m = 1; m < 64; m <<= 1) sm += __shfl_xor(sm, m);
        if (lane == 0) red[4 + w] = sm;
        __syncthreads();
        sm = red[4] + red[5] + red[6] + red[7];
        attW[((size_t)(t0 + tt) * 128 + b) * 256 + tid] = e / sm;
        __syncthreads();
    }
}

// ------------------------------------------------------------ glimpse
// glim[t,b,c] = sum_p feat[b,p,c] * attW[t,b,p]
__global__ __launch_bounds__(256) void glimpse_kernel(
    const ushort* __restrict__ feat, const float* __restrict__ attW,
    ushort* __restrict__ glim) {
    __shared__ float attS[31][256];
    const int tid = threadIdx.x;
    const int b = blockIdx.x >> 1, ch = blockIdx.x & 1;
    const int c0 = ch << 8;
    for (int idx = tid; idx < 31 * 256; idx += 256) {
        const int tt = idx >> 8, p = idx & 255;
        attS[tt][p] = attW[((size_t)tt * 128 + b) * 256 + p];
    }
    __syncthreads();
    float acc[31];
#pragma unroll
    for (int tt = 0; tt < 31; ++tt) acc[tt] = 0.f;
    for (int p = 0; p < 256; ++p) {
        const float fv = b2f(feat[((size_t)(b * 256 + p) << 9) + c0 + tid]);
#pragma unroll
        for (int tt = 0; tt < 31; ++tt) acc[tt] += fv * attS[tt][p];
    }
#pragma unroll
    for (int tt = 0; tt < 31; ++tt)
        glim[((size_t)tt * 128 + b) * 512 + c0 + tid] = f2b(acc[tt]);
}

// ------------------------------------------------------------ logits
// out[b,t,v] = [h1 | glimpse] @ out_W + out_b. One block per (t,b).
__global__ __launch_bounds__(128) void logits_kernel(
    const ushort* __restrict__ H1all, const ushort* __restrict__ glim,
    const float* __restrict__ outWf, const float* __restrict__ outBf,
    void* __restrict__ out, const int* __restrict__ flag) {
    __shared__ float arow[1024];
    const int r = blockIdx.x, tt = r >> 7, b = r & 127;
    const int tid = threadIdx.x;
    for (int idx = tid; idx < 512; idx += 128) {
        arow[idx] = b2f(H1all[(size_t)r * 512 + idx]);
        arow[512 + idx] = b2f(glim[(size_t)r * 512 + idx]);
    }
    __syncthreads();
    if (tid < 111) {
        float a = outBf[tid];
        for (int k = 0; k < 1024; ++k)
            a += arow[k] * outWf[k * 111 + tid];
        const size_t oi = ((size_t)b * 31 + tt) * 111 + tid;
        if (*flag) ((float*)out)[oi] = a;
        else       ((ushort*)out)[oi] = f2b(a);
    }
}

// ------------------------------------------------------------ launch
extern "C" void kernel_launch(void* const* d_in, const int* in_sizes, int n_in,
                              void* d_out, int out_size, void* d_ws, size_t ws_size,
                              hipStream_t stream) {
    (void)in_sizes; (void)n_in; (void)out_size;
    const void* features = d_in[0];
    const void* holistic = d_in[1];
    const int*  gt       = (const int*)d_in[2];
    const void* embed_W  = d_in[3];
    const void* k0 = d_in[4];
    const void* rk0 = d_in[5];
    const void* b0 = d_in[6];
    const void* k1 = d_in[7];
    const void* rk1 = d_in[8];
    const void* b1 = d_in[9];
    const void* Wh = d_in[10];
    const void* Wf = d_in[11];
    const void* bfv = d_in[12];
    const void* wa = d_in[13];
    const void* outW = d_in[14];
    const void* outB = d_in[15];

    char* ws = (char*)d_ws;
    size_t off = 0;
    auto take = [&](size_t bytes) -> char* {
        char* p = ws + off;
        off += (bytes + 255) & ~(size_t)255;
        return p;
    };
    int*    flag  = (int*)take(256);
    ushort* featB = (ushort*)take(16777216ull * 2);      // 33.5 MB
    ushort* holB  = (ushort*)take(65536ull * 2);
    ushort* embB  = (ushort*)take(56832ull * 2);
    float*  b0f   = (float*)take(2048ull * 4);
    float*  b1f   = (float*)take(2048ull * 4);
    float*  bff   = (float*)take(512ull * 4);
    float*  waf   = (float*)take(512ull * 4);
    float*  outBf = (float*)take(111ull * 4);
    float*  outWf = (float*)take(113664ull * 4);
    ushort* fproj = (ushort*)take(32768ull * 512 * 2);   // 33.5 MB
    ushort* WfT   = (ushort*)take(4608ull * 512 * 2);
    ushort* k0T   = (ushort*)take(2048ull * 512 * 2);
    ushort* rk0T  = (ushort*)take(2048ull * 512 * 2);
    ushort* k1T   = (ushort*)take(2048ull * 512 * 2);
    ushort* rk1T  = (ushort*)take(2048ull * 512 * 2);
    ushort* WhT   = (ushort*)take(512ull * 512 * 2);
    float*  E0    = (float*)take(111ull * 2048 * 4);
    ushort* h0b0  = (ushort*)take(128ull * 512 * 2);
    ushort* h0b1  = (ushort*)take(128ull * 512 * 2);
    ushort* h1b0  = (ushort*)take(128ull * 512 * 2);
    ushort* h1b1  = (ushort*)take(128ull * 512 * 2);
    float*  c0buf = (float*)take(128ull * 512 * 4);
    float*  c1buf = (float*)take(128ull * 512 * 4);
    ushort* H1all = (ushort*)take(3968ull * 512 * 2);
    float*  HP    = (float*)take(3968ull * 512 * 4);
    float*  attW  = (float*)take(31ull * 128 * 256 * 4);
    ushort* glim  = (ushort*)take(3968ull * 512 * 2);
    if (off > ws_size) return;   // leaves output zeroed -> absmax 0.114 signals this

    // 0) dtype detect + canonicalize
    detect_dtype<<<dim3(1), dim3(64), 0, stream>>>(features, flag);
    cvt_bf16<<<dim3(65536), dim3(256), 0, stream>>>(features, featB, 16777216, flag);
    cvt_bf16<<<dim3(256), dim3(256), 0, stream>>>(holistic, holB, 65536, flag);
    cvt_bf16<<<dim3(222), dim3(256), 0, stream>>>(embed_W, embB, 56832, flag);
    cvt_f32<<<dim3(8), dim3(256), 0, stream>>>(b0, b0f, 2048, flag);
    cvt_f32<<<dim3(8), dim3(256), 0, stream>>>(b1, b1f, 2048, flag);
    cvt_f32<<<dim3(2), dim3(256), 0, stream>>>(bfv, bff, 512, flag);
    cvt_f32<<<dim3(2), dim3(256), 0, stream>>>(wa, waf, 512, flag);
    cvt_f32<<<dim3(1), dim3(256), 0, stream>>>(outB, outBf, 111, flag);
    cvt_f32<<<dim3(444), dim3(256), 0, stream>>>(outW, outWf, 113664, flag);
    // 1) weight transposes (any dtype in, bf16 out)
    transpose_any<<<dim3(16 * 64), dim3(256), 0, stream>>>(k0, k0T, 512, 2048, flag);
    transpose_any<<<dim3(16 * 64), dim3(256), 0, stream>>>(rk0, rk0T, 512, 2048, flag);
    transpose_any<<<dim3(16 * 64), dim3(256), 0, stream>>>(k1, k1T, 512, 2048, flag);
    transpose_any<<<dim3(16 * 64), dim3(256), 0, stream>>>(rk1, rk1T, 512, 2048, flag);
    transpose_any<<<dim3(16 * 16), dim3(256), 0, stream>>>(Wh, WhT, 512, 512, flag);
    transpose_any<<<dim3(144 * 16), dim3(256), 0, stream>>>(Wf, WfT, 4608, 512, flag);
    // 2) conv fproj (timestep-invariant)
    conv_fproj<<<dim3(1024), dim3(256), 0, stream>>>(featB, WfT, bff, fproj);
    // 3) E0 = embed_W @ k0
    gemm_bt<<<dim3(16), dim3(256), 0, stream>>>(embB, k0T, E0, 111, 2048, 512);
    // 4) recurrence
    for (int t = -2; t <= 31; ++t)
        lstm_stage<<<dim3(128), dim3(256), 0, stream>>>(t, holB, gt, b0f, b1f,
            k0T, rk0T, k1T, rk1T, E0, h0b0, h0b1, h1b0, h1b1, c0buf, c1buf, H1all);
    // 5) batched attention epilogue
    gemm_bt<<<dim3(31 * 4), dim3(256), 0, stream>>>(H1all, WhT, HP, 3968, 512, 512);
    attention_kernel<<<dim3(256), dim3(256), 0, stream>>>(fproj, HP, waf, attW);
    glimpse_kernel<<<dim3(256), dim3(256), 0, stream>>>(featB, attW, glim);
    logits_kernel<<<dim3(3968), dim3(128), 0, stream>>>(H1all, glim, outWf, outBf, d_out, flag);
}

// Round 3
// 1277.644 us; speedup vs baseline: 1.7805x; 1.7805x over previous
//
#include <hip/hip_runtime.h>

// SARDecoder on MI355X (gfx950). Dtype-robust (runtime bf16-vs-fp32 detect).
//
// Pipeline:
//  0) detect dtype; canonicalize inputs
//  1) transpose weights (BT layout for MFMA B-fragments)
//  2) conv3x3 fproj via 9-tap shifted MFMA GEMM (timestep invariant)
//  3) E0 = embed_W @ k0 (one-hot gather trick)
//  4) 34x lstm_stage (stage0(t) + stage1(t-1) per launch), fast activations
//  5) HP = H1 @ Wh (MFMA); att_logits (broadcast-LDS tanh attention);
//     glimpse (fused softmax) -> HG=[H1|glim]; logits = HG @ out_W^T (MFMA)

typedef __bf16 bf16;
typedef bf16 bf16x8 __attribute__((ext_vector_type(8)));
typedef float f32x4 __attribute__((ext_vector_type(4)));

#define MFMA16(a, b, c) __builtin_amdgcn_mfma_f32_16x16x32_bf16((a), (b), (c), 0, 0, 0)

__device__ __forceinline__ float b2f(unsigned short u) {
    return __uint_as_float(((unsigned int)u) << 16);
}
__device__ __forceinline__ unsigned short f2b(float f) {
    unsigned int x = __float_as_uint(f);
    unsigned int r = (x + 0x7fffu + ((x >> 16) & 1u)) >> 16;   // RNE
    return (unsigned short)r;
}
// branchless fast activations: v_exp_f32 + v_rcp_f32 (~1ulp each)
__device__ __forceinline__ float tanh_fast(float x) {
    const float e = exp2f(2.885390082f * x);                   // 2/ln2
    return 1.0f - 2.0f * __builtin_amdgcn_rcpf(e + 1.0f);
}
__device__ __forceinline__ float sig_fast(float x) {
    return __builtin_amdgcn_rcpf(1.0f + exp2f(-1.44269504f * x));
}

// ------------------------------------------------------------ dtype detect
__global__ void detect_dtype(const void* __restrict__ feat, int* __restrict__ flag) {
    if (threadIdx.x == 0 && blockIdx.x == 0) {
        const ushort* u = (const ushort*)feat;
        int cnt = 0;
        for (int i = 0; i < 128; i += 2) {
            const int e = (u[i] >> 7) & 0xFF;
            if (e >= 96 && e <= 150) ++cnt;
        }
        *flag = (cnt >= 40) ? 0 : 1;
    }
}

// ------------------------------------------------------------ converters
__global__ __launch_bounds__(256) void cvt_bf16(
    const void* __restrict__ src, ushort* __restrict__ dst, int n,
    const int* __restrict__ flag) {
    const int i = blockIdx.x * 256 + threadIdx.x;
    if (i >= n) return;
    if (*flag) dst[i] = f2b(((const float*)src)[i]);
    else       dst[i] = ((const ushort*)src)[i];
}

__global__ __launch_bounds__(256) void cvt_f32(
    const void* __restrict__ src, float* __restrict__ dst, int n,
    const int* __restrict__ flag) {
    const int i = blockIdx.x * 256 + threadIdx.x;
    if (i >= n) return;
    if (*flag) dst[i] = ((const float*)src)[i];
    else       dst[i] = b2f(((const ushort*)src)[i]);
}

// ------------------------------------------------------------ transpose
__global__ __launch_bounds__(256) void transpose_any(
    const void* __restrict__ in, ushort* __restrict__ out, int R, int C,
    const int* __restrict__ flag) {
    __shared__ float s[32][33];
    const int f32 = *flag;
    const int nbc = C >> 5;
    const int rb = blockIdx.x / nbc, cb = blockIdx.x % nbc;
    const int tx = threadIdx.x & 31, ty = threadIdx.x >> 5;
#pragma unroll
    for (int k = 0; k < 4; ++k) {
        const size_t idx = (size_t)(rb * 32 + ty + k * 8) * C + cb * 32 + tx;
        s[ty + k * 8][tx] = f32 ? ((const float*)in)[idx] : b2f(((const ushort*)in)[idx]);
    }
    __syncthreads();
#pragma unroll
    for (int k = 0; k < 4; ++k)
        out[(size_t)(cb * 32 + ty + k * 8) * R + rb * 32 + tx] = f2b(s[tx][ty + k * 8]);
}

// ------------------------------------------------------------ outW^T pad
// WoTpad[v][k] = outW[k][v] for v<111 else 0.  (128 x 1024 bf16)
__global__ __launch_bounds__(256) void woT_build(
    const float* __restrict__ outWf, ushort* __restrict__ WoTpad) {
    const int i = blockIdx.x * 256 + threadIdx.x;
    if (i >= 131072) return;
    const int v = i >> 10, k = i & 1023;
    WoTpad[i] = (v < 111) ? f2b(outWf[k * 111 + v]) : (ushort)0;
}

// ------------------------------------------------------------ conv fproj
__global__ __launch_bounds__(256) void conv_fproj(
    const ushort* __restrict__ feat, const ushort* __restrict__ WfT,
    const float* __restrict__ bff, ushort* __restrict__ fproj) {
    __shared__ __align__(16) bf16 As[128][72];
    __shared__ __align__(16) bf16 Bs[128][72];
    const int tid = threadIdx.x;
    const int rb = blockIdx.x >> 2;
    const int nb = blockIdx.x & 3;
    const int b = rb >> 1;
    const int p0 = (rb & 1) << 7;
    const int ar = tid >> 1;
    const int ah = (tid & 1) << 5;
    const int p = p0 + ar, y = p >> 5, x = p & 31;
    const int w = tid >> 6, lane = tid & 63, l15 = lane & 15, q = lane >> 4;
    const int wr = (w >> 1) << 6, wc = (w & 1) << 6;
    f32x4 acc[4][4] = {};
    for (int kb = 0; kb < 72; ++kb) {
        const int tap = kb >> 3, c0 = (kb & 7) << 6;
        const int yy = y + tap / 3 - 1, xx = x + tap % 3 - 1;
        const bool valid = (yy >= 0) && (yy < 8) && (xx >= 0) && (xx < 32);
        const int yc = valid ? yy : 0, xc = valid ? xx : 0;
        const uint4 z4 = {0u, 0u, 0u, 0u};
        const uint4* asrc = (const uint4*)(feat + ((size_t)((b * 8 + yc) * 32 + xc) * 512 + c0 + ah));
        uint4 a0 = asrc[0], a1 = asrc[1], a2 = asrc[2], a3 = asrc[3];
        if (!valid) { a0 = z4; a1 = z4; a2 = z4; a3 = z4; }
        const uint4* bsrc = (const uint4*)(WfT + (size_t)(nb * 128 + ar) * 4608 + kb * 64 + ah);
        uint4 b0v = bsrc[0], b1v = bsrc[1], b2v = bsrc[2], b3v = bsrc[3];
        __syncthreads();
        *(uint4*)&As[ar][ah] = a0;
        *(uint4*)&As[ar][ah + 8] = a1;
        *(uint4*)&As[ar][ah + 16] = a2;
        *(uint4*)&As[ar][ah + 24] = a3;
        *(uint4*)&Bs[ar][ah] = b0v;
        *(uint4*)&Bs[ar][ah + 8] = b1v;
        *(uint4*)&Bs[ar][ah + 16] = b2v;
        *(uint4*)&Bs[ar][ah + 24] = b3v;
        __syncthreads();
#pragma unroll
        for (int ks = 0; ks < 64; ks += 32) {
            bf16x8 af[4], bfr[4];
#pragma unroll
            for (int i = 0; i < 4; ++i) af[i] = *(const bf16x8*)&As[wr + i * 16 + l15][ks + q * 8];
#pragma unroll
            for (int j = 0; j < 4; ++j) bfr[j] = *(const bf16x8*)&Bs[wc + j * 16 + l15][ks + q * 8];
#pragma unroll
            for (int i = 0; i < 4; ++i)
#pragma unroll
                for (int j = 0; j < 4; ++j)
                    acc[i][j] = MFMA16(af[i], bfr[j], acc[i][j]);
        }
    }
    const int rowbase = rb * 128 + wr, colbase = nb * 128 + wc;
#pragma unroll
    for (int i = 0; i < 4; ++i)
#pragma unroll
        for (int j = 0; j < 4; ++j)
#pragma unroll
            for (int rr = 0; rr < 4; ++rr) {
                const int row = rowbase + i * 16 + q * 4 + rr;
                const int col = colbase + j * 16 + l15;
                fproj[(size_t)row * 512 + col] = f2b(acc[i][j][rr] + bff[col]);
            }
}

// ------------------------------------------------------------ generic GEMM
// C[M x N] (fp32) = A[M x K, lda] (bf16) * BT[N x K]^T. M may be ragged.
__global__ __launch_bounds__(256) void gemm_bt(
    const ushort* __restrict__ A, const ushort* __restrict__ BT,
    float* __restrict__ C, int M, int N, int K, int lda) {
    __shared__ __align__(16) bf16 As[128][72];
    __shared__ __align__(16) bf16 Bs[128][72];
    const int tid = threadIdx.x;
    const int nnb = N >> 7;
    const int rb = blockIdx.x / nnb, nb = blockIdx.x % nnb;
    const int ar = tid >> 1, ah = (tid & 1) << 5;
    const int w = tid >> 6, lane = tid & 63, l15 = lane & 15, q = lane >> 4;
    const int wr = (w >> 1) << 6, wc = (w & 1) << 6;
    const int r_glob = rb * 128 + ar;
    const bool aval = (r_glob < M);
    const int r_ld = aval ? r_glob : 0;
    f32x4 acc[4][4] = {};
    const int nkb = K >> 6;
    for (int kb = 0; kb < nkb; ++kb) {
        const uint4 z4 = {0u, 0u, 0u, 0u};
        const uint4* asrc = (const uint4*)(A + (size_t)r_ld * lda + kb * 64 + ah);
        uint4 a0 = asrc[0], a1 = asrc[1], a2 = asrc[2], a3 = asrc[3];
        if (!aval) { a0 = z4; a1 = z4; a2 = z4; a3 = z4; }
        const uint4* bsrc = (const uint4*)(BT + (size_t)(nb * 128 + ar) * K + kb * 64 + ah);
        uint4 b0v = bsrc[0], b1v = bsrc[1], b2v = bsrc[2], b3v = bsrc[3];
        __syncthreads();
        *(uint4*)&As[ar][ah] = a0;
        *(uint4*)&As[ar][ah + 8] = a1;
        *(uint4*)&As[ar][ah + 16] = a2;
        *(uint4*)&As[ar][ah + 24] = a3;
        *(uint4*)&Bs[ar][ah] = b0v;
        *(uint4*)&Bs[ar][ah + 8] = b1v;
        *(uint4*)&Bs[ar][ah + 16] = b2v;
        *(uint4*)&Bs[ar][ah + 24] = b3v;
        __syncthreads();
#pragma unroll
        for (int ks = 0; ks < 64; ks += 32) {
            bf16x8 af[4], bfr[4];
#pragma unroll
            for (int i = 0; i < 4; ++i) af[i] = *(const bf16x8*)&As[wr + i * 16 + l15][ks + q * 8];
#pragma unroll
            for (int j = 0; j < 4; ++j) bfr[j] = *(const bf16x8*)&Bs[wc + j * 16 + l15][ks + q * 8];
#pragma unroll
            for (int i = 0; i < 4; ++i)
#pragma unroll
                for (int j = 0; j < 4; ++j)
                    acc[i][j] = MFMA16(af[i], bfr[j], acc[i][j]);
        }
    }
#pragma unroll
    for (int i = 0; i < 4; ++i)
#pragma unroll
        for (int j = 0; j < 4; ++j)
#pragma unroll
            for (int rr = 0; rr < 4; ++rr) {
                const int row = rb * 128 + wr + i * 16 + q * 4 + rr;
                const int col = nb * 128 + wc + j * 16 + l15;
                if (row < M) C[(size_t)row * N + col] = acc[i][j][rr];
            }
}

// ------------------------------------------------------------ LSTM stage
// blocks 0..63: stage0 of step t; blocks 64..127: stage1 of step t-1.
__global__ __launch_bounds__(256) void lstm_stage(
    int t,
    const ushort* __restrict__ holistic, const int* __restrict__ gt,
    const float* __restrict__ b0f, const float* __restrict__ b1f,
    const ushort* __restrict__ k0T, const ushort* __restrict__ rk0T,
    const ushort* __restrict__ k1T, const ushort* __restrict__ rk1T,
    const float* __restrict__ E0,
    ushort* h0b0, ushort* h0b1, ushort* h1b0, ushort* h1b1,
    float* c0buf, float* c1buf, ushort* HG) {
    const int part = blockIdx.x >> 6;
    const int bi = blockIdx.x & 63;
    const ushort *A1 = nullptr, *A2 = nullptr, *B1 = nullptr, *B2 = nullptr;
    const float* bias = nullptr;
    ushort *hout = nullptr, *hout2 = nullptr;
    float* cbuf = nullptr;
    bool useC = false, useE = false;
    int nkb = 8;
    if (part == 0) {
        if (!(t == -2 || (t >= 0 && t <= 30))) return;
        bias = b0f; cbuf = c0buf;
        if (t == -2) { A1 = holistic; B1 = k0T; hout = h0b1; }
        else {
            A1 = ((t + 1) & 1) ? h0b1 : h0b0;
            B1 = rk0T;
            hout = (t & 1) ? h0b1 : h0b0;
            useC = true; useE = true;
        }
    } else {
        if (!(t == -1 || (t >= 1 && t <= 31))) return;
        bias = b1f; cbuf = c1buf;
        if (t == -1) { A1 = h0b1; B1 = k1T; hout = h1b1; }
        else {
            const int s = t - 1;
            A1 = (s & 1) ? h0b1 : h0b0;           // h0 of step s
            A2 = ((s + 1) & 1) ? h1b1 : h1b0;     // h1 of step s-1
            B1 = k1T; B2 = rk1T;
            hout = (s & 1) ? h1b1 : h1b0;
            hout2 = HG + (size_t)s * 131072;      // row stride 1024, first half
            useC = true; nkb = 16;
        }
    }
    const int m0 = (bi >> 4) << 5;
    const int cc0 = (bi & 15) << 5;
    const int tid = threadIdx.x;
    const int w = tid >> 6, lane = tid & 63, l15 = lane & 15, q = lane >> 4;
    __shared__ __align__(16) bf16 As[32][72];
    __shared__ __align__(16) bf16 Bs[4][32][72];
    __shared__ float zs[4][32][33];
    f32x4 acc[2][2] = {};
    const int arr = tid >> 3, aco = (tid & 7) << 3;
    const int bn = lane >> 1, bho = (lane & 1) << 5;
    for (int kb = 0; kb < nkb; ++kb) {
        const ushort* ap = (kb < 8) ? (A1 + (size_t)(m0 + arr) * 512 + kb * 64 + aco)
                                    : (A2 + (size_t)(m0 + arr) * 512 + (kb - 8) * 64 + aco);
        uint4 av = *(const uint4*)ap;
        const ushort* bp = (kb < 8) ? (B1 + (size_t)(w * 512 + cc0 + bn) * 512 + kb * 64 + bho)
                                    : (B2 + (size_t)(w * 512 + cc0 + bn) * 512 + (kb - 8) * 64 + bho);
        uint4 bv0 = ((const uint4*)bp)[0];
        uint4 bv1 = ((const uint4*)bp)[1];
        uint4 bv2 = ((const uint4*)bp)[2];
        uint4 bv3 = ((const uint4*)bp)[3];
        __syncthreads();
        *(uint4*)&As[arr][aco] = av;
        *(uint4*)&Bs[w][bn][bho] = bv0;
        *(uint4*)&Bs[w][bn][bho + 8] = bv1;
        *(uint4*)&Bs[w][bn][bho + 16] = bv2;
        *(uint4*)&Bs[w][bn][bho + 24] = bv3;
        __syncthreads();
#pragma unroll
        for (int ks = 0; ks < 64; ks += 32) {
            bf16x8 af0 = *(const bf16x8*)&As[l15][ks + q * 8];
            bf16x8 af1 = *(const bf16x8*)&As[16 + l15][ks + q * 8];
            bf16x8 bf0 = *(const bf16x8*)&Bs[w][l15][ks + q * 8];
            bf16x8 bf1 = *(const bf16x8*)&Bs[w][16 + l15][ks + q * 8];
            acc[0][0] = MFMA16(af0, bf0, acc[0][0]);
            acc[0][1] = MFMA16(af0, bf1, acc[0][1]);
            acc[1][0] = MFMA16(af1, bf0, acc[1][0]);
            acc[1][1] = MFMA16(af1, bf1, acc[1][1]);
        }
    }
    __syncthreads();
#pragma unroll
    for (int i = 0; i < 2; ++i)
#pragma unroll
        for (int j = 0; j < 2; ++j)
#pragma unroll
            for (int rr = 0; rr < 4; ++rr)
                zs[w][i * 16 + q * 4 + rr][j * 16 + l15] = acc[i][j][rr];
    __syncthreads();
    for (int e = tid; e < 1024; e += 256) {
        const int mm = e >> 5, cc = e & 31;
        const int brow = m0 + mm, col = cc0 + cc;
        float zi = zs[0][mm][cc] + bias[col];
        float zf = zs[1][mm][cc] + bias[512 + col];
        float zg = zs[2][mm][cc] + bias[1024 + col];
        float zo = zs[3][mm][cc] + bias[1536 + col];
        if (useE) {
            const int s = (t == 0) ? 111 : gt[brow * 31 + t - 1];
            if (s >= 0 && s < 111) {
                const float* er = E0 + (size_t)s * 2048;
                zi += er[col]; zf += er[512 + col]; zg += er[1024 + col]; zo += er[1536 + col];
            }
        }
        const float cp = useC ? cbuf[brow * 512 + col] : 0.0f;
        const float c2 = sig_fast(zf) * cp + sig_fast(zi) * tanh_fast(zg);
        const float h = sig_fast(zo) * tanh_fast(c2);
        cbuf[brow * 512 + col] = c2;
        hout[brow * 512 + col] = f2b(h);
        if (hout2) hout2[brow * 1024 + col] = f2b(h);
    }
}

// ------------------------------------------------------------ attention logits
// attL[t,b,p] = sum_c tanh(fproj[b,p,c] + HP[t,b,c]) * wa[c]
// Block = (b, p-half). Lane owns p; c loops serially -> hpS reads are
// wave-uniform broadcasts (zero bank conflicts); fproj reads are bf16x8.
__global__ __launch_bounds__(256) void att_logits(
    const ushort* __restrict__ fproj, const float* __restrict__ HP,
    const float* __restrict__ waf, float* __restrict__ attL) {
    __shared__ float hpS[31][512];        // 63.5 KB
    __shared__ float waS[512];            // 2 KB
    __shared__ float accS[128][33];       // 16.9 KB (half-combine, padded)
    const int tid = threadIdx.x;
    const int b = blockIdx.x >> 1, ph = blockIdx.x & 1;
    const int pl = tid & 127, ch = tid >> 7;
    const int p = ph * 128 + pl;
    for (int i = tid; i < 31 * 512; i += 256) {
        const int tt = i >> 9, c = i & 511;
        hpS[tt][c] = HP[((size_t)tt * 128 + b) * 512 + c];
    }
    waS[tid] = waf[tid];
    if (tid < 256) waS[256 + tid] = waf[256 + tid];
    __syncthreads();
    float acc[31];
#pragma unroll
    for (int tt = 0; tt < 31; ++tt) acc[tt] = 0.f;
    const ushort* frow = fproj + (size_t)(b * 256 + p) * 512 + ch * 256;
    for (int c8 = 0; c8 < 32; ++c8) {
        const int cc = ch * 256 + c8 * 8;
        const uint4 fv = *(const uint4*)(frow + c8 * 8);
        float f[8];
        f[0] = b2f((unsigned short)(fv.x & 0xffff)); f[1] = b2f((unsigned short)(fv.x >> 16));
        f[2] = b2f((unsigned short)(fv.y & 0xffff)); f[3] = b2f((unsigned short)(fv.y >> 16));
        f[4] = b2f((unsigned short)(fv.z & 0xffff)); f[5] = b2f((unsigned short)(fv.z >> 16));
        f[6] = b2f((unsigned short)(fv.w & 0xffff)); f[7] = b2f((unsigned short)(fv.w >> 16));
        float w8[8];
#pragma unroll
        for (int j = 0; j < 8; ++j) w8[j] = waS[cc + j];
#pragma unroll
        for (int tt = 0; tt < 31; ++tt) {
            const float* hp8 = &hpS[tt][cc];   // wave-uniform -> broadcast
            float s = 0.f;
#pragma unroll
            for (int j = 0; j < 8; ++j)
                s += tanh_fast(f[j] + hp8[j]) * w8[j];
            acc[tt] += s;
        }
    }
    if (ch == 1) {
#pragma unroll
        for (int tt = 0; tt < 31; ++tt) accS[pl][tt] = acc[tt];
    }
    __syncthreads();
    if (ch == 0) {
#pragma unroll
        for (int tt = 0; tt < 31; ++tt)
            attL[((size_t)tt * 128 + b) * 256 + p] = acc[tt] + accS[pl][tt];
    }
}

// ------------------------------------------------------------ glimpse (+softmax)
// softmax_p over attL rows, then glim[t,b,c] = sum_p feat[b,p,c]*att[t,b,p].
// Writes into HG second half (columns 512..1023).
__global__ __launch_bounds__(256) void glimpse_kernel(
    const ushort* __restrict__ feat, const float* __restrict__ attL,
    ushort* __restrict__ HG) {
    __shared__ float attS[31][256];
    const int tid = threadIdx.x;
    const int b = blockIdx.x >> 1, chh = blockIdx.x & 1;
    const int c0 = chh << 8;
    const int w = tid >> 6, lane = tid & 63;
    for (int i = tid; i < 31 * 256; i += 256) {
        const int tt = i >> 8, p = i & 255;
        attS[tt][p] = attL[((size_t)tt * 128 + b) * 256 + p];
    }
    __syncthreads();
    for (int tt = w; tt < 31; tt += 4) {
        float v0 = attS[tt][lane], v1 = attS[tt][lane + 64];
        float v2 = attS[tt][lane + 128], v3 = attS[tt][lane + 192];
        float mx = fmaxf(fmaxf(v0, v1), fmaxf(v2, v3));
#pragma unroll
        for (int m = 1; m < 64; m <<= 1) mx = fmaxf(mx, __shfl_xor(mx, m));
        const float e0 = expf(v0 - mx), e1 = expf(v1 - mx);
        const float e2 = expf(v2 - mx), e3 = expf(v3 - mx);
        float s = e0 + e1 + e2 + e3;
#pragma unroll
        for (int m = 1; m < 64; m <<= 1) s += __shfl_xor(s, m);
        const float r = 1.0f / s;
        attS[tt][lane] = e0 * r;  attS[tt][lane + 64] = e1 * r;
        attS[tt][lane + 128] = e2 * r;  attS[tt][lane + 192] = e3 * r;
    }
    __syncthreads();
    float acc[31];
#pragma unroll
    for (int tt = 0; tt < 31; ++tt) acc[tt] = 0.f;
    for (int p = 0; p < 256; ++p) {
        const float fv = b2f(feat[((size_t)(b * 256 + p) << 9) + c0 + tid]);
#pragma unroll
        for (int tt = 0; tt < 31; ++tt) acc[tt] += fv * attS[tt][p];
    }
#pragma unroll
    for (int tt = 0; tt < 31; ++tt)
        HG[((size_t)tt * 128 + b) * 1024 + 512 + c0 + tid] = f2b(acc[tt]);
}

// ------------------------------------------------------------ logits store
__global__ __launch_bounds__(256) void logits_store(
    const float* __restrict__ C, const float* __restrict__ outBf,
    void* __restrict__ out, const int* __restrict__ flag) {
    const int i = blockIdx.x * 256 + threadIdx.x;
    if (i >= 3968 * 111) return;
    const int r = i / 111, v = i - r * 111;
    const int tt = r >> 7, b = r & 127;
    const float a = C[(size_t)r * 128 + v] + outBf[v];
    const size_t oi = ((size_t)b * 31 + tt) * 111 + v;
    if (*flag) ((float*)out)[oi] = a;
    else       ((ushort*)out)[oi] = f2b(a);
}

// ------------------------------------------------------------ launch
extern "C" void kernel_launch(void* const* d_in, const int* in_sizes, int n_in,
                              void* d_out, int out_size, void* d_ws, size_t ws_size,
                              hipStream_t stream) {
    (void)in_sizes; (void)n_in; (void)out_size;
    const void* features = d_in[0];
    const void* holistic = d_in[1];
    const int*  gt       = (const int*)d_in[2];
    const void* embed_W  = d_in[3];
    const void* k0 = d_in[4];
    const void* rk0 = d_in[5];
    const void* b0 = d_in[6];
    const void* k1 = d_in[7];
    const void* rk1 = d_in[8];
    const void* b1 = d_in[9];
    const void* Wh = d_in[10];
    const void* Wf = d_in[11];
    const void* bfv = d_in[12];
    const void* wa = d_in[13];
    const void* outW = d_in[14];
    const void* outB = d_in[15];

    char* ws = (char*)d_ws;
    size_t off = 0;
    auto take = [&](size_t bytes) -> char* {
        char* p = ws + off;
        off += (bytes + 255) & ~(size_t)255;
        return p;
    };
    int*    flag  = (int*)take(256);
    ushort* featB = (ushort*)take(16777216ull * 2);
    ushort* holB  = (ushort*)take(65536ull * 2);
    ushort* embB  = (ushort*)take(56832ull * 2);
    float*  b0f   = (float*)take(2048ull * 4);
    float*  b1f   = (float*)take(2048ull * 4);
    float*  bff   = (float*)take(512ull * 4);
    float*  waf   = (float*)take(512ull * 4);
    float*  outBf = (float*)take(111ull * 4);
    float*  outWf = (float*)take(113664ull * 4);
    ushort* fproj = (ushort*)take(32768ull * 512 * 2);
    ushort* WfT   = (ushort*)take(4608ull * 512 * 2);
    ushort* k0T   = (ushort*)take(2048ull * 512 * 2);
    ushort* rk0T  = (ushort*)take(2048ull * 512 * 2);
    ushort* k1T   = (ushort*)take(2048ull * 512 * 2);
    ushort* rk1T  = (ushort*)take(2048ull * 512 * 2);
    ushort* WhT   = (ushort*)take(512ull * 512 * 2);
    float*  E0    = (float*)take(111ull * 2048 * 4);
    ushort* h0b0  = (ushort*)take(128ull * 512 * 2);
    ushort* h0b1  = (ushort*)take(128ull * 512 * 2);
    ushort* h1b0  = (ushort*)take(128ull * 512 * 2);
    ushort* h1b1  = (ushort*)take(128ull * 512 * 2);
    float*  c0buf = (float*)take(128ull * 512 * 4);
    float*  c1buf = (float*)take(128ull * 512 * 4);
    ushort* HG    = (ushort*)take(3968ull * 1024 * 2);   // [H1 | glimpse]
    float*  HP    = (float*)take(3968ull * 512 * 4);
    float*  attL  = (float*)take(31ull * 128 * 256 * 4);
    // aliases (stream-serial: attL fully consumed by glimpse before these writes)
    float*  Cout   = (float*)attL;                        // 3968*128 fp32
    ushort* WoTpad = (ushort*)((char*)attL + 3968ull * 128 * 4);  // 128*1024 bf16
    if (off > ws_size) return;

    // 0) dtype detect + canonicalize
    detect_dtype<<<dim3(1), dim3(64), 0, stream>>>(features, flag);
    cvt_bf16<<<dim3(65536), dim3(256), 0, stream>>>(features, featB, 16777216, flag);
    cvt_bf16<<<dim3(256), dim3(256), 0, stream>>>(holistic, holB, 65536, flag);
    cvt_bf16<<<dim3(222), dim3(256), 0, stream>>>(embed_W, embB, 56832, flag);
    cvt_f32<<<dim3(8), dim3(256), 0, stream>>>(b0, b0f, 2048, flag);
    cvt_f32<<<dim3(8), dim3(256), 0, stream>>>(b1, b1f, 2048, flag);
    cvt_f32<<<dim3(2), dim3(256), 0, stream>>>(bfv, bff, 512, flag);
    cvt_f32<<<dim3(2), dim3(256), 0, stream>>>(wa, waf, 512, flag);
    cvt_f32<<<dim3(1), dim3(256), 0, stream>>>(outB, outBf, 111, flag);
    cvt_f32<<<dim3(444), dim3(256), 0, stream>>>(outW, outWf, 113664, flag);
    // 1) weight transposes
    transpose_any<<<dim3(16 * 64), dim3(256), 0, stream>>>(k0, k0T, 512, 2048, flag);
    transpose_any<<<dim3(16 * 64), dim3(256), 0, stream>>>(rk0, rk0T, 512, 2048, flag);
    transpose_any<<<dim3(16 * 64), dim3(256), 0, stream>>>(k1, k1T, 512, 2048, flag);
    transpose_any<<<dim3(16 * 64), dim3(256), 0, stream>>>(rk1, rk1T, 512, 2048, flag);
    transpose_any<<<dim3(16 * 16), dim3(256), 0, stream>>>(Wh, WhT, 512, 512, flag);
    transpose_any<<<dim3(144 * 16), dim3(256), 0, stream>>>(Wf, WfT, 4608, 512, flag);
    // 2) conv fproj
    conv_fproj<<<dim3(1024), dim3(256), 0, stream>>>(featB, WfT, bff, fproj);
    // 3) E0 = embed_W @ k0
    gemm_bt<<<dim3(16), dim3(256), 0, stream>>>(embB, k0T, E0, 111, 2048, 512, 512);
    // 4) recurrence
    for (int t = -2; t <= 31; ++t)
        lstm_stage<<<dim3(128), dim3(256), 0, stream>>>(t, holB, gt, b0f, b1f,
            k0T, rk0T, k1T, rk1T, E0, h0b0, h0b1, h1b0, h1b1, c0buf, c1buf, HG);
    // 5) batched epilogue
    gemm_bt<<<dim3(31 * 4), dim3(256), 0, stream>>>(HG, WhT, HP, 3968, 512, 512, 1024);
    att_logits<<<dim3(256), dim3(256), 0, stream>>>(fproj, HP, waf, attL);
    glimpse_kernel<<<dim3(256), dim3(256), 0, stream>>>(featB, attL, HG);
    woT_build<<<dim3(512), dim3(256), 0, stream>>>(outWf, WoTpad);
    gemm_bt<<<dim3(31), dim3(256), 0, stream>>>(HG, WoTpad, Cout, 3968, 128, 1024, 1024);
    logits_store<<<dim3(1721), dim3(256), 0, stream>>>(Cout, outBf, d_out, flag);
}